// Round 7
// baseline (10994.170 us; speedup 1.0000x reference)
//
#include <hip/hip_runtime.h>
#include <math.h>

#define TT 4096
#define HH 1500
#define NB 125     // blocks; each owns 12 hidden units
#define NT 512     // 8 waves: 0..5 matvec (wave = 2 units, 8 gate rows),
                   //          6 = x-proj + poll, 7 = poll + gates + publish
#define NREP 8     // pub replicas (reader sharding; bid&7 ~ XCD id)

typedef unsigned uv4 __attribute__((ext_vector_type(4)));
typedef _Float16 h2f __attribute__((ext_vector_type(2)));
typedef _Float16 h4f __attribute__((ext_vector_type(4)));

#define ALD4(p)   __hip_atomic_load((p), __ATOMIC_RELAXED, __HIP_MEMORY_SCOPE_AGENT)
#define AST4(p,v) __hip_atomic_store((p), (v), __ATOMIC_RELAXED, __HIP_MEMORY_SCOPE_AGENT)
#define AST8(p,v) __hip_atomic_store((p), (v), __ATOMIC_RELAXED, __HIP_MEMORY_SCOPE_AGENT)

__device__ __forceinline__ float fast_sigmoid(float z) {
  return 1.0f / (1.0f + __expf(-z));
}
__device__ __forceinline__ float fast_tanh(float z) {
  float az = fabsf(z);
  float e  = __expf(-2.0f * az);
  float r  = (1.0f - e) / (1.0f + e);
  return copysignf(r, z);
}
// fp16 pair dot with fp32 accumulate (v_dot2_f32_f16)
__device__ __forceinline__ float dot2(unsigned wb, unsigned hb, float acc) {
#if __has_builtin(__builtin_amdgcn_fdot2)
  return __builtin_amdgcn_fdot2(__builtin_bit_cast(h2f, wb),
                                __builtin_bit_cast(h2f, hb), acc, false);
#else
  h2f w = __builtin_bit_cast(h2f, wb), h = __builtin_bit_cast(h2f, hb);
  acc = fmaf((float)w.x, (float)h.x, acc);
  return fmaf((float)w.y, (float)h.y, acc);
#endif
}

// R18: depth-2 pipelined poll at NB=125 (structure = R17, best @10.03ms).
// R17 post-mortem: FETCH/WRITE halved with N but time ~flat -> period is a
// SERIAL LATENCY CHAIN (~4.7kcy of visibility+detect per step), not
// congestion. Last confounded lever: sampling quantization. Old round =
// 3xload, vmcnt(0), check, sleep64 ~ L+160cy -> detect ~ L + U(0,L+160),
// maxed over 250 poll-waves. R16's no-sleep depth-3 test of this regressed
// at 6x the request rate of this probe (250blk x 384 pollers, continuous);
// confounded. Here: TWO pinned register sets (v[40:51] / v[52:63]); each
// iteration issues one 3-load set and vmcnt(3)-waits the PREVIOUS set ->
// sample lands every ~L/2 at only 2x R17's request rate, sleep retained.
// Exit wave-uniform (v_cmp/s_cbranch_vccz); vmcnt(0) drain on exit is
// same-or-newer identical data (slot content write-once per step; per-dword
// tags make epoch mixing harmless).
__device__ __forceinline__ void spin_poll2(
    const unsigned* p0, const unsigned* p1, const unsigned* p2,
    unsigned tag, unsigned liv, uv4& o0, uv4& o1, uv4& o2) {
  unsigned t, t2, ac;
  unsigned r0, r1, r2, r3, r4, r5, r6, r7, r8, r9, r10, r11;
  asm volatile(
      "global_load_dwordx4 v[40:43], %[p0], off sc0 sc1\n\t"
      "global_load_dwordx4 v[44:47], %[p1], off sc0 sc1\n\t"
      "global_load_dwordx4 v[48:51], %[p2], off sc0 sc1\n\t"
      "2:\n\t"
      "global_load_dwordx4 v[52:55], %[p0], off sc0 sc1\n\t"
      "global_load_dwordx4 v[56:59], %[p1], off sc0 sc1\n\t"
      "global_load_dwordx4 v[60:63], %[p2], off sc0 sc1\n\t"
      "s_waitcnt vmcnt(3)\n\t"
      // ---- check set A (v40-51) ----
      "v_xor_b32 %[t], %[tg], v40\n\t"
      "v_and_b32 %[ac], 15, %[t]\n\t"
      "v_xor_b32 %[t], %[tg], v41\n\t"
      "v_and_or_b32 %[ac], %[t], 15, %[ac]\n\t"
      "v_xor_b32 %[t], %[tg], v42\n\t"
      "v_and_or_b32 %[ac], %[t], 15, %[ac]\n\t"
      "v_xor_b32 %[t], %[tg], v43\n\t"
      "v_and_or_b32 %[ac], %[t], 15, %[ac]\n\t"
      "v_xor_b32 %[t], %[tg], v44\n\t"
      "v_and_or_b32 %[ac], %[t], 15, %[ac]\n\t"
      "v_xor_b32 %[t], %[tg], v45\n\t"
      "v_and_or_b32 %[ac], %[t], 15, %[ac]\n\t"
      "v_xor_b32 %[t], %[tg], v46\n\t"
      "v_and_or_b32 %[ac], %[t], 15, %[ac]\n\t"
      "v_xor_b32 %[t], %[tg], v47\n\t"
      "v_and_or_b32 %[ac], %[t], 15, %[ac]\n\t"
      "v_xor_b32 %[t], %[tg], v48\n\t"
      "v_and_b32 %[t2], 15, %[t]\n\t"
      "v_xor_b32 %[t], %[tg], v49\n\t"
      "v_and_or_b32 %[t2], %[t], 15, %[t2]\n\t"
      "v_xor_b32 %[t], %[tg], v50\n\t"
      "v_and_or_b32 %[t2], %[t], 15, %[t2]\n\t"
      "v_xor_b32 %[t], %[tg], v51\n\t"
      "v_and_or_b32 %[t2], %[t], 15, %[t2]\n\t"
      "v_and_or_b32 %[ac], %[t2], %[lv], %[ac]\n\t"
      "v_cmp_ne_u32 vcc, 0, %[ac]\n\t"
      "s_cbranch_vccz 5f\n\t"
      "s_sleep 1\n\t"
      // ---- phase 2: reissue A, check set B (v52-63) ----
      "global_load_dwordx4 v[40:43], %[p0], off sc0 sc1\n\t"
      "global_load_dwordx4 v[44:47], %[p1], off sc0 sc1\n\t"
      "global_load_dwordx4 v[48:51], %[p2], off sc0 sc1\n\t"
      "s_waitcnt vmcnt(3)\n\t"
      "v_xor_b32 %[t], %[tg], v52\n\t"
      "v_and_b32 %[ac], 15, %[t]\n\t"
      "v_xor_b32 %[t], %[tg], v53\n\t"
      "v_and_or_b32 %[ac], %[t], 15, %[ac]\n\t"
      "v_xor_b32 %[t], %[tg], v54\n\t"
      "v_and_or_b32 %[ac], %[t], 15, %[ac]\n\t"
      "v_xor_b32 %[t], %[tg], v55\n\t"
      "v_and_or_b32 %[ac], %[t], 15, %[ac]\n\t"
      "v_xor_b32 %[t], %[tg], v56\n\t"
      "v_and_or_b32 %[ac], %[t], 15, %[ac]\n\t"
      "v_xor_b32 %[t], %[tg], v57\n\t"
      "v_and_or_b32 %[ac], %[t], 15, %[ac]\n\t"
      "v_xor_b32 %[t], %[tg], v58\n\t"
      "v_and_or_b32 %[ac], %[t], 15, %[ac]\n\t"
      "v_xor_b32 %[t], %[tg], v59\n\t"
      "v_and_or_b32 %[ac], %[t], 15, %[ac]\n\t"
      "v_xor_b32 %[t], %[tg], v60\n\t"
      "v_and_b32 %[t2], 15, %[t]\n\t"
      "v_xor_b32 %[t], %[tg], v61\n\t"
      "v_and_or_b32 %[t2], %[t], 15, %[t2]\n\t"
      "v_xor_b32 %[t], %[tg], v62\n\t"
      "v_and_or_b32 %[t2], %[t], 15, %[t2]\n\t"
      "v_xor_b32 %[t], %[tg], v63\n\t"
      "v_and_or_b32 %[t2], %[t], 15, %[t2]\n\t"
      "v_and_or_b32 %[ac], %[t2], %[lv], %[ac]\n\t"
      "v_cmp_ne_u32 vcc, 0, %[ac]\n\t"
      "s_cbranch_vccz 6f\n\t"
      "s_sleep 1\n\t"
      "s_branch 2b\n\t"
      "5:\n\t"   // exit with set A valid
      "s_waitcnt vmcnt(0)\n\t"
      "v_mov_b32 %[q0], v40\n\t"
      "v_mov_b32 %[q1], v41\n\t"
      "v_mov_b32 %[q2], v42\n\t"
      "v_mov_b32 %[q3], v43\n\t"
      "v_mov_b32 %[q4], v44\n\t"
      "v_mov_b32 %[q5], v45\n\t"
      "v_mov_b32 %[q6], v46\n\t"
      "v_mov_b32 %[q7], v47\n\t"
      "v_mov_b32 %[q8], v48\n\t"
      "v_mov_b32 %[q9], v49\n\t"
      "v_mov_b32 %[q10], v50\n\t"
      "v_mov_b32 %[q11], v51\n\t"
      "s_branch 7f\n\t"
      "6:\n\t"   // exit with set B valid
      "s_waitcnt vmcnt(0)\n\t"
      "v_mov_b32 %[q0], v52\n\t"
      "v_mov_b32 %[q1], v53\n\t"
      "v_mov_b32 %[q2], v54\n\t"
      "v_mov_b32 %[q3], v55\n\t"
      "v_mov_b32 %[q4], v56\n\t"
      "v_mov_b32 %[q5], v57\n\t"
      "v_mov_b32 %[q6], v58\n\t"
      "v_mov_b32 %[q7], v59\n\t"
      "v_mov_b32 %[q8], v60\n\t"
      "v_mov_b32 %[q9], v61\n\t"
      "v_mov_b32 %[q10], v62\n\t"
      "v_mov_b32 %[q11], v63\n\t"
      "7:"
      : [t]"=&v"(t), [t2]"=&v"(t2), [ac]"=&v"(ac),
        [q0]"=&v"(r0), [q1]"=&v"(r1), [q2]"=&v"(r2), [q3]"=&v"(r3),
        [q4]"=&v"(r4), [q5]"=&v"(r5), [q6]"=&v"(r6), [q7]"=&v"(r7),
        [q8]"=&v"(r8), [q9]"=&v"(r9), [q10]"=&v"(r10), [q11]"=&v"(r11)
      : [p0]"v"(p0), [p1]"v"(p1), [p2]"v"(p2), [tg]"v"(tag), [lv]"v"(liv)
      : "memory", "vcc",
        "v40","v41","v42","v43","v44","v45","v46","v47",
        "v48","v49","v50","v51","v52","v53","v54","v55",
        "v56","v57","v58","v59","v60","v61","v62","v63");
  o0.x = r0;  o0.y = r1;  o0.z = r2;  o0.w = r3;
  o1.x = r4;  o1.y = r5;  o1.z = r6;  o1.w = r7;
  o2.x = r8;  o2.y = r9;  o2.z = r10; o2.w = r11;
}
__device__ __forceinline__ h4f cvt4h(uv4 v) {
  h4f r;
  r.x = (_Float16)__uint_as_float(v.x);
  r.y = (_Float16)__uint_as_float(v.y);
  r.z = (_Float16)__uint_as_float(v.z);
  r.w = (_Float16)__uint_as_float(v.w);
  return r;
}

__global__
__attribute__((amdgpu_flat_work_group_size(NT, NT), amdgpu_waves_per_eu(2, 2)))
void lstm_fused(
    const float* __restrict__ x,    // (4096, 20)
    const float* __restrict__ Wih,  // (6000, 20)
    const float* __restrict__ Whh,  // (6000, 1500)
    const float* __restrict__ bih,  // (6000,)
    const float* __restrict__ bhh,  // (6000,)
    const float* __restrict__ W1,   // (1875, 1500)
    const float* __restrict__ b1,   // (1875,)
    const float* __restrict__ W2,   // (20, 1875)
    const float* __restrict__ b2,   // (20,)
    float* __restrict__ out,        // (20,)
    unsigned* __restrict__ ws)
{
  const int tid = threadIdx.x;
  const int bid = blockIdx.x;
  const int wv  = tid >> 6;   // wave 0..7
  const int ln  = tid & 63;

  // pub: [NREP][2][1536] tagged dwords; block b owns dwords 12b..12b+11 of
  // each replica/slot. hidp after.
  unsigned* pub  = ws;
  unsigned* hidp = ws + NREP * 2 * 1536;   // [1875] tagged hid values

  // weights: 48 rows (r=u*4+g) x 1536 halves (1500 + zero pad) = 147,456 B
  __shared__ __align__(16) _Float16 lds_wh[48 * 1536];
  __shared__ __align__(16) _Float16 lds_hh[1536];  // h(t) as fp16
  __shared__ __align__(16) float    lds_hf[1536];  // h(TT) fp32 for MLP
  __shared__ float lds_xp[2][48];                  // x-proj dbuf: [par][g*12+u]
  __shared__ float lds_gs[4][12];                  // gate sums: [g][u]
  float* lds_hd = (float*)lds_wh;                  // alias (block 0, post-loop)
  // total ~157.2 KB < 160 KiB -> exactly 1 block/CU (lockstep chain intact)

  // ---- stage W_hh slice into LDS, converting fp32 -> fp16 ----
  for (int hi = tid; hi < 48 * 1536; hi += NT) {
    const int r = hi / 1536, k = hi - r * 1536;
    const int u = r >> 2, g = r & 3;
    const size_t grow = (size_t)(g * HH + bid * 12 + u) * HH;
    const float v = (k < HH) ? Whh[grow + k] : 0.f;
    lds_wh[hi] = (_Float16)v;
  }

  // matvec bases (waves 0..5): wave wv owns units 2wv, 2wv+1; 192 b128/row
  const int uu = (wv < 6) ? wv : 0;
  const uv4* wpA = ((const uv4*)lds_wh) + (size_t)(2 * uu) * 4 * 192;
  const uv4* wpB = wpA + 4 * 192;
  const uv4* hp = (const uv4*)lds_hh;

  // ---- wave 6 lanes 0..47: persistent Wih row (g=ln/12, u=ln%12) + x(0) ----
  float4 wx0, wx1, wx2, wx3, wx4;
  float4 xr0, xr1, xr2, xr3, xr4;
  float bias = 0.f;
  if (wv == 6 && ln < 48) {
    const int g = ln / 12, u = ln - g * 12;
    const int row = g * HH + bid * 12 + u;
    const float4* sp = (const float4*)(Wih + row * 20);
    wx0 = sp[0]; wx1 = sp[1]; wx2 = sp[2]; wx3 = sp[3]; wx4 = sp[4];
    bias = bih[row] + bhh[row];
    const float4* xx = (const float4*)x;
    xr0 = xx[0]; xr1 = xx[1]; xr2 = xx[2]; xr3 = xx[3]; xr4 = xx[4];
  }

  float c = 0.f;  // cell state: wave 7 lanes 0..11 (unit = ln)

  // init publish: h(0)=0 with tag 1 into ALL replicas, slot 0
  if (tid < 12 * NREP)
    AST4(pub + (tid / 12) * 3072 + 12 * bid + (tid % 12), 1u);

  __syncthreads();   // weights staged

  // this block's poll replica
  unsigned* myrep = pub + (bid & (NREP - 1)) * 3072;

  for (int t = 0; t < TT; ++t) {
    const int s = t & 1;
    const unsigned tag = (unsigned)((t + 1) & 15);

    // ================= P phase (pre-A) =================
    uv4 pw[24];
    if (wv < 6) {
      // prefetch ALL 24 weight b128 (96 VGPRs) — overlaps the poll below
      #pragma unroll
      for (int g = 0; g < 4; ++g) {
        #pragma unroll
        for (int m = 0; m < 3; ++m) {
          pw[g * 3 + m]      = wpA[g * 192 + ln + 64 * m];
          pw[12 + g * 3 + m] = wpB[g * 192 + ln + 64 * m];
        }
      }
    } else {
      if (wv == 6 && ln < 48) {
        // x-projection for step t (from registers, h-independent)
        float sx = bias;
        sx += wx0.x*xr0.x + wx0.y*xr0.y + wx0.z*xr0.z + wx0.w*xr0.w;
        sx += wx1.x*xr1.x + wx1.y*xr1.y + wx1.z*xr1.z + wx1.w*xr1.w;
        sx += wx2.x*xr2.x + wx2.y*xr2.y + wx2.z*xr2.z + wx2.w*xr2.w;
        sx += wx3.x*xr3.x + wx3.y*xr3.y + wx3.z*xr3.z + wx3.w*xr3.w;
        sx += wx4.x*xr4.x + wx4.y*xr4.y + wx4.z*xr4.z + wx4.w*xr4.w;
        lds_xp[s][ln] = sx;
      }
      // ---- depth-2 pipelined tagged poll of replica bid&7 ----
      const int p4 = (tid - 384) << 2;        // 0,4,...,508
      unsigned* base = myrep + s * 1536;
      const unsigned liv = (p4 + 1024 < HH) ? 0xFu : 0u;   // 1500 = 4*375
      uv4 v0, v1, v2;
      spin_poll2(base + p4, base + p4 + 512, base + p4 + 1024,
                 tag, liv, v0, v1, v2);
      *(h4f*)(lds_hh + p4)       = cvt4h(v0);
      *(h4f*)(lds_hh + p4 + 512) = cvt4h(v1);
      h4f z = {(_Float16)0.f, (_Float16)0.f, (_Float16)0.f, (_Float16)0.f};
      *(h4f*)(lds_hh + p4 + 1024) = (p4 + 1024 < HH) ? cvt4h(v2) : z;
    }
    __syncthreads();   // ---- A: h(t) fp16, xp(t) staged ----

    // ================= M phase =================
    if (wv < 6) {
      uv4 hv[3];
      #pragma unroll
      for (int m = 0; m < 3; ++m) hv[m] = hp[ln + 64 * m];
      float a0[4] = {0.f, 0.f, 0.f, 0.f};
      float a1[4] = {0.f, 0.f, 0.f, 0.f};
      #pragma unroll
      for (int g = 0; g < 4; ++g) {
        #pragma unroll
        for (int m = 0; m < 3; ++m) {
          const uv4 h = hv[m];
          const uv4 qa = pw[g * 3 + m];
          a0[g] = dot2(qa.x, h.x, a0[g]);
          a0[g] = dot2(qa.y, h.y, a0[g]);
          a0[g] = dot2(qa.z, h.z, a0[g]);
          a0[g] = dot2(qa.w, h.w, a0[g]);
          const uv4 qb = pw[12 + g * 3 + m];
          a1[g] = dot2(qb.x, h.x, a1[g]);
          a1[g] = dot2(qb.y, h.y, a1[g]);
          a1[g] = dot2(qb.z, h.z, a1[g]);
          a1[g] = dot2(qb.w, h.w, a1[g]);
        }
      }
      // fold-select reduce (x2 units)
      #pragma unroll
      for (int g = 0; g < 4; ++g) {
        a0[g] += __shfl_xor(a0[g], 16, 64);
        a0[g] += __shfl_xor(a0[g], 32, 64);
        a1[g] += __shfl_xor(a1[g], 16, 64);
        a1[g] += __shfl_xor(a1[g], 32, 64);
      }
      const int q4 = ln >> 4;
      float v0 = (q4 == 0) ? a0[0] : (q4 == 1) ? a0[1] : (q4 == 2) ? a0[2] : a0[3];
      float v1 = (q4 == 0) ? a1[0] : (q4 == 1) ? a1[1] : (q4 == 2) ? a1[2] : a1[3];
      #pragma unroll
      for (int off = 1; off <= 8; off <<= 1) {
        v0 += __shfl_xor(v0, off, 64);
        v1 += __shfl_xor(v1, off, 64);
      }
      if ((ln & 15) == 0) {
        lds_gs[q4][2 * wv]     = v0;
        lds_gs[q4][2 * wv + 1] = v1;
      }
    } else if (wv == 6 && ln < 48 && (t + 1) < TT) {
      // prefetch x(t+1) while waves 0-5 compute
      const float4* xx = (const float4*)(x + 20 * (t + 1));
      xr0 = xx[0]; xr1 = xx[1]; xr2 = xx[2]; xr3 = xx[3]; xr4 = xx[4];
    }
    __syncthreads();   // ---- B: gate sums ready ----

    // ================= G phase: wave 7 only =================
    if (wv == 7) {
      unsigned bits = 0u;
      if (ln < 12) {
        const int u = ln;
        const float zi = lds_gs[0][u] + lds_xp[s][0 + u];
        const float zf = lds_gs[1][u] + lds_xp[s][12 + u];
        const float zg = lds_gs[2][u] + lds_xp[s][24 + u];
        const float zo = lds_gs[3][u] + lds_xp[s][36 + u];
        const float ig = fast_sigmoid(zi);
        const float fg = fast_sigmoid(zf);
        const float gg = fast_tanh(zg);
        const float og = fast_sigmoid(zo);
        c = fg * c + ig * gg;
        const float hn = og * fast_tanh(c);
        bits = (__float_as_uint(hn) & ~15u) | (unsigned)((t + 2) & 15);
      }
      // publish 12 tagged dwords x 8 replicas: lanes 0..47, dwordx2 each
      const int m6 = ln % 6;
      const unsigned d0 = (unsigned)__shfl((int)bits, 2 * m6, 64);
      const unsigned d1 = (unsigned)__shfl((int)bits, 2 * m6 + 1, 64);
      if (ln < 48) {
        const int rep = ln / 6;
        const unsigned long long dd =
            (unsigned long long)d0 | ((unsigned long long)d1 << 32);
        AST8((unsigned long long*)(pub + rep * 3072 + ((t + 1) & 1) * 1536 +
                                   12 * bid + 2 * m6), dd);
      }
    }
  }

  // ---- final gather h(TT) fp32 into lds_hf (slot 0, tag 1) ----
  {
    const unsigned tagf = (unsigned)((TT + 1) & 15);
    if (tid < 375) {
      const unsigned* ap = myrep + (tid << 2);   // slot 0 of own replica
      uv4 v;
      for (;;) {
        asm volatile("global_load_dwordx4 %0, %1, off sc0 sc1\n\t"
                     "s_waitcnt vmcnt(0)"
                     : "=&v"(v) : "v"(ap) : "memory");
        const unsigned miss = ((v.x & 15u) ^ tagf) | ((v.y & 15u) ^ tagf)
                            | ((v.z & 15u) ^ tagf) | ((v.w & 15u) ^ tagf);
        if (!miss) break;
        __builtin_amdgcn_s_sleep(1);
      }
      float4 f = {__uint_as_float(v.x), __uint_as_float(v.y),
                  __uint_as_float(v.z), __uint_as_float(v.w)};
      *(float4*)(lds_hf + (tid << 2)) = f;
    } else if (tid < 384) {
      float4 z4 = {0.f, 0.f, 0.f, 0.f};
      *(float4*)(lds_hf + (tid << 2)) = z4;
    }
  }
  __syncthreads();

  // ---- MLP layer 1: 15 rows/block, r = bid + 125*k, k = wv, wv+8 ----
  {
    const float4* h4 = (const float4*)lds_hf;
    for (int k = wv; k < 15; k += 8) {
      const int r = bid + NB * k;
      const float4* wrow = (const float4*)(W1 + (size_t)r * HH);
      float ss = 0.f;
      #pragma unroll
      for (int m = 0; m < 6; ++m) {
        const int idx = ln + 64 * m;
        if (idx < 375) {
          const float4 a = wrow[idx], hv = h4[idx];
          ss += a.x*hv.x + a.y*hv.y + a.z*hv.z + a.w*hv.w;
        }
      }
      #pragma unroll
      for (int off = 32; off > 0; off >>= 1) ss += __shfl_xor(ss, off, 64);
      if (ln == 0) {
        const float vv = ss + b1[r];
        AST4(hidp + r, (__float_as_uint(vv) & ~15u) | 5u);  // tag 5 != poison 10
      }
    }
  }
  if (bid != 0) return;

  // ---- block 0: gather hid (into lds_wh alias), MLP layer 2, write out ----
  __syncthreads();
  for (int j = tid; j < 1875; j += NT) {
    unsigned bts;
    for (;;) {
      bts = ALD4(hidp + j);
      if ((bts & 15u) == 5u) break;
      __builtin_amdgcn_s_sleep(1);
    }
    lds_hd[j] = __uint_as_float(bts);
  }
  __syncthreads();

  for (int r = wv; r < 20; r += 8) {
    float ss = 0.f;
    for (int k = ln; k < 1875; k += 64)
      ss = fmaf(W2[(size_t)r * 1875 + k], lds_hd[k], ss);
    #pragma unroll
    for (int off = 32; off > 0; off >>= 1) ss += __shfl_xor(ss, off, 64);
    if (ln == 0) out[r] = ss + b2[r];
  }
}

extern "C" void kernel_launch(void* const* d_in, const int* in_sizes, int n_in,
                              void* d_out, int out_size, void* d_ws, size_t ws_size,
                              hipStream_t stream) {
  const float* x   = (const float*)d_in[0];
  const float* Wih = (const float*)d_in[1];
  const float* Whh = (const float*)d_in[2];
  const float* bih = (const float*)d_in[3];
  const float* bhh = (const float*)d_in[4];
  const float* W1  = (const float*)d_in[5];
  const float* b1  = (const float*)d_in[6];
  const float* W2  = (const float*)d_in[7];
  const float* b2  = (const float*)d_in[8];
  float* out   = (float*)d_out;
  unsigned* ws = (unsigned*)d_ws;   // uses ~106 KB (8 pub replicas + hidp)

  // 125 blocks x 512 threads, ~157 KB LDS (1 block/CU), 125 <= 256 CUs:
  // all blocks co-resident -> the tagged exchange cannot deadlock.
  hipLaunchKernelGGL(lstm_fused, dim3(NB), dim3(NT), 0, stream,
                     x, Wih, Whh, bih, bhh, W1, b1, W2, b2, out, ws);
}

// Round 8
// 10472.449 us; speedup vs baseline: 1.0498x; 1.0498x over previous
//
#include <hip/hip_runtime.h>
#include <math.h>

#define TT 4096
#define HH 1500
#define NB 125     // blocks; each owns 12 hidden units
#define NT 512     // 8 waves: 0..5 slice-waves (poll own 1/6 of h + partial
                   //          matvec), 6 = x-proj, 7 = gates + publish
#define NREP 8     // pub replicas (reader sharding; bid&7 ~ XCD id)

typedef unsigned uv4 __attribute__((ext_vector_type(4)));
typedef _Float16 h2f __attribute__((ext_vector_type(2)));
typedef _Float16 h4f __attribute__((ext_vector_type(4)));

#define ALD4(p)   __hip_atomic_load((p), __ATOMIC_RELAXED, __HIP_MEMORY_SCOPE_AGENT)
#define AST4(p,v) __hip_atomic_store((p), (v), __ATOMIC_RELAXED, __HIP_MEMORY_SCOPE_AGENT)
#define AST8(p,v) __hip_atomic_store((p), (v), __ATOMIC_RELAXED, __HIP_MEMORY_SCOPE_AGENT)

__device__ __forceinline__ float fast_sigmoid(float z) {
  return 1.0f / (1.0f + __expf(-z));
}
__device__ __forceinline__ float fast_tanh(float z) {
  float az = fabsf(z);
  float e  = __expf(-2.0f * az);
  float r  = (1.0f - e) / (1.0f + e);
  return copysignf(r, z);
}
// fp16 pair dot with fp32 accumulate (v_dot2_f32_f16)
__device__ __forceinline__ float dot2(unsigned wb, unsigned hb, float acc) {
#if __has_builtin(__builtin_amdgcn_fdot2)
  return __builtin_amdgcn_fdot2(__builtin_bit_cast(h2f, wb),
                                __builtin_bit_cast(h2f, hb), acc, false);
#else
  h2f w = __builtin_bit_cast(h2f, wb), h = __builtin_bit_cast(h2f, hb);
  acc = fmaf((float)w.x, (float)h.x, acc);
  return fmaf((float)w.y, (float)h.y, acc);
#endif
}

// R19: k-sliced matvec, per-slice arrival (structure = R17, best @10.03ms).
// Ledger: replicas -12%, req width -7%, coupling 0, lines -10%R, schedule
// -45%R, sampling -20%R/-9%R, population -4% win. The detect equilibrium is
// immovable; the remaining lever is OVERLAP: today M (~500cy) runs AFTER the
// last straggler because every wave waits for ALL of h. The matvec is
// associative in k: wave w needs only k-slice w. So wave w polls ONLY its
// 64 h-chunks (1 lane : 1 chunk, wave-uniform exit), stages into a PRIVATE
// lds_hs[w] (no cross-wave handoff -> barrier A deleted), and computes 48
// row-partials over its slice the moment the slice lands -> M hides under
// the straggler tail. Weights for the slice are prefetched into 128 VGPRs
// BEFORE the poll (LDS traffic hidden under the wait, as R17's P phase did);
// slices XOR-swizzled (c^(r&31)) at staging to kill the 32-way row-stride
// bank conflict. Partials -> lds_ps[2][6][48] (parity dbuf; wave-7 lag is
// barrier-bounded to 1 step). ONE barrier/step; wave 7 sums 6 partials/row,
// gates, publishes (R17's coalesced 48-lane publish, unchanged).
__device__ __forceinline__ h4f cvt4h(uv4 v) {
  h4f r;
  r.x = (_Float16)__uint_as_float(v.x);
  r.y = (_Float16)__uint_as_float(v.y);
  r.z = (_Float16)__uint_as_float(v.z);
  r.w = (_Float16)__uint_as_float(v.w);
  return r;
}

__global__
__attribute__((amdgpu_flat_work_group_size(NT, NT), amdgpu_waves_per_eu(2, 2)))
void lstm_fused(
    const float* __restrict__ x,    // (4096, 20)
    const float* __restrict__ Wih,  // (6000, 20)
    const float* __restrict__ Whh,  // (6000, 1500)
    const float* __restrict__ bih,  // (6000,)
    const float* __restrict__ bhh,  // (6000,)
    const float* __restrict__ W1,   // (1875, 1500)
    const float* __restrict__ b1,   // (1875,)
    const float* __restrict__ W2,   // (20, 1875)
    const float* __restrict__ b2,   // (20,)
    float* __restrict__ out,        // (20,)
    unsigned* __restrict__ ws)
{
  const int tid = threadIdx.x;
  const int bid = blockIdx.x;
  const int wv  = tid >> 6;   // wave 0..7
  const int ln  = tid & 63;

  // pub: [NREP][2][1536] tagged dwords; block b owns dwords 12b..12b+11 of
  // each replica/slot. hidp after.
  unsigned* pub  = ws;
  unsigned* hidp = ws + NREP * 2 * 1536;   // [1875] tagged hid values

  // weights: 48 rows (r=u*4+g) x 1536 halves; within each 256-half k-slice,
  // chunk c stored at position c^(r&31) (bank-conflict swizzle)
  __shared__ __align__(16) _Float16 lds_wh[48 * 1536];   // 147,456 B
  __shared__ __align__(16) _Float16 lds_hs[6][256];      // per-wave h slices
  __shared__ __align__(16) float    lds_hf[1536];        // h(TT) fp32 for MLP
  __shared__ float lds_xp[2][48];    // x-proj dbuf: [par][g*12+u]
  __shared__ float lds_ps[2][6][48]; // partial sums: [par][wave][row]
  float* lds_hd = (float*)lds_wh;    // alias (block 0, post-loop)
  // total ~159.4 KB < 160 KiB -> exactly 1 block/CU (lockstep chain intact)

  // ---- stage W_hh slice into LDS (fp32 -> fp16, slice-swizzled) ----
  for (int hi = tid; hi < 48 * 1536; hi += NT) {
    const int r = hi / 1536, k = hi - r * 1536;
    const int u = r >> 2, g = r & 3;
    const float v = (k < HH) ? Whh[(size_t)(g * HH + bid * 12 + u) * HH + k]
                             : 0.f;
    const int w = k >> 8, o = k & 255, cch = o >> 3, j = o & 7;
    const int cs = cch ^ (r & 31);
    lds_wh[r * 1536 + w * 256 + cs * 8 + j] = (_Float16)v;
  }
  // pre-zero the pad tail of slice 5 (chunks 375..383 are never polled)
  if (wv == 5 && ln >= 55) {
    h4f z = {(_Float16)0.f, (_Float16)0.f, (_Float16)0.f, (_Float16)0.f};
    *(h4f*)(lds_hs[5] + 4 * ln) = z;
  }

  // ---- wave 6 lanes 0..47: persistent Wih row (g=ln/12, u=ln%12) + x(0) ----
  float4 wx0, wx1, wx2, wx3, wx4;
  float4 xr0, xr1, xr2, xr3, xr4;
  float bias = 0.f;
  if (wv == 6 && ln < 48) {
    const int g = ln / 12, u = ln - g * 12;
    const int row = g * HH + bid * 12 + u;
    const float4* sp = (const float4*)(Wih + row * 20);
    wx0 = sp[0]; wx1 = sp[1]; wx2 = sp[2]; wx3 = sp[3]; wx4 = sp[4];
    bias = bih[row] + bhh[row];
    const float4* xx = (const float4*)x;
    xr0 = xx[0]; xr1 = xx[1]; xr2 = xx[2]; xr3 = xx[3]; xr4 = xx[4];
  }

  float c = 0.f;  // cell state: wave 7 lanes 0..11 (unit = ln)

  // init publish: h(0)=0 with tag 1 into ALL replicas, slot 0
  if (tid < 12 * NREP)
    AST4(pub + (tid / 12) * 3072 + 12 * bid + (tid % 12), 1u);

  __syncthreads();   // weights staged, hs pad zeroed

  // this block's poll replica
  unsigned* myrep = pub + (bid & (NREP - 1)) * 3072;

  // slice-wave bindings (waves 0..5): lane ln polls chunk 64*wv+ln
  const int q    = (wv << 6) | ln;            // 0..383; live 0..374
  const int live = (q < 375);
  const int qc   = live ? q : 0;
  // weight slice base for row ln (<48), slice wv
  const _Float16* wr = lds_wh + ln * 1536 + (wv << 8);

  for (int t = 0; t < TT; ++t) {
    const int s = t & 1;
    const unsigned tag = (unsigned)((t + 1) & 15);

    if (wv < 6) {
      // ---- prefetch this row's 32 weight chunks into VGPRs (hidden
      //      under the poll wait; LDS reads complete while we spin) ----
      uv4 pw[32];
      if (ln < 48) {
        #pragma unroll
        for (int cc = 0; cc < 32; ++cc)
          pw[cc] = *(const uv4*)(wr + ((cc ^ (ln & 31)) << 3));
      }
      // ---- per-lane poll of OWN chunk; wave-uniform exit ----
      const unsigned* ap = myrep + s * 1536 + (qc << 2);
      uv4 v;
      for (;;) {
        asm volatile("global_load_dwordx4 %0, %1, off sc0 sc1\n\t"
                     "s_waitcnt vmcnt(0)"
                     : "=&v"(v) : "v"(ap) : "memory");
        unsigned miss = 0u;
        if (live)
          miss = ((v.x & 15u) ^ tag) | ((v.y & 15u) ^ tag)
               | ((v.z & 15u) ^ tag) | ((v.w & 15u) ^ tag);
        if (!__any(miss != 0u)) break;
        __builtin_amdgcn_s_sleep(1);
      }
      if (live) *(h4f*)(lds_hs[wv] + 4 * ln) = cvt4h(v);
      // ---- partial matvec over OWN slice: lane = row, 32 chunk-dots ----
      if (ln < 48) {
        const uv4* hsl = (const uv4*)lds_hs[wv];
        float ps = 0.f;
        #pragma unroll
        for (int cc = 0; cc < 32; ++cc) {
          const uv4 hq = hsl[cc];
          const uv4 wq = pw[cc];
          ps = dot2(wq.x, hq.x, ps);
          ps = dot2(wq.y, hq.y, ps);
          ps = dot2(wq.z, hq.z, ps);
          ps = dot2(wq.w, hq.w, ps);
        }
        lds_ps[s][wv][ln] = ps;
      }
    } else if (wv == 6) {
      if (ln < 48) {
        // x-projection for step t (from registers, h-independent)
        float sx = bias;
        sx += wx0.x*xr0.x + wx0.y*xr0.y + wx0.z*xr0.z + wx0.w*xr0.w;
        sx += wx1.x*xr1.x + wx1.y*xr1.y + wx1.z*xr1.z + wx1.w*xr1.w;
        sx += wx2.x*xr2.x + wx2.y*xr2.y + wx2.z*xr2.z + wx2.w*xr2.w;
        sx += wx3.x*xr3.x + wx3.y*xr3.y + wx3.z*xr3.z + wx3.w*xr3.w;
        sx += wx4.x*xr4.x + wx4.y*xr4.y + wx4.z*xr4.z + wx4.w*xr4.w;
        lds_xp[s][ln] = sx;
        if (t + 1 < TT) {   // prefetch x(t+1)
          const float4* xx = (const float4*)(x + 20 * (t + 1));
          xr0 = xx[0]; xr1 = xx[1]; xr2 = xx[2]; xr3 = xx[3]; xr4 = xx[4];
        }
      }
    }
    // wave 7 falls through to the barrier
    __syncthreads();   // ---- ps(s) + xp(s) ready ----

    // ================= G phase: wave 7 only (others run ahead) ==========
    if (wv == 7) {
      unsigned bits = 0u;
      if (ln < 12) {
        float4 a = {0.f, 0.f, 0.f, 0.f};
        #pragma unroll
        for (int w = 0; w < 6; ++w) {
          const float4 p = *(const float4*)&lds_ps[s][w][ln << 2];
          a.x += p.x; a.y += p.y; a.z += p.z; a.w += p.w;
        }
        const float zi = a.x + lds_xp[s][0 + ln];
        const float zf = a.y + lds_xp[s][12 + ln];
        const float zg = a.z + lds_xp[s][24 + ln];
        const float zo = a.w + lds_xp[s][36 + ln];
        const float ig = fast_sigmoid(zi);
        const float fg = fast_sigmoid(zf);
        const float gg = fast_tanh(zg);
        const float og = fast_sigmoid(zo);
        c = fg * c + ig * gg;
        const float hn = og * fast_tanh(c);
        bits = (__float_as_uint(hn) & ~15u) | (unsigned)((t + 2) & 15);
      }
      // publish 12 tagged dwords x 8 replicas: lanes 0..47, dwordx2 each
      const int m6 = ln % 6;
      const unsigned d0 = (unsigned)__shfl((int)bits, 2 * m6, 64);
      const unsigned d1 = (unsigned)__shfl((int)bits, 2 * m6 + 1, 64);
      if (ln < 48) {
        const int rep = ln / 6;
        const unsigned long long dd =
            (unsigned long long)d0 | ((unsigned long long)d1 << 32);
        AST8((unsigned long long*)(pub + rep * 3072 + ((t + 1) & 1) * 1536 +
                                   12 * bid + 2 * m6), dd);
      }
    }
  }

  // ---- final gather h(TT) fp32 into lds_hf (slot 0, tag 1) ----
  {
    const unsigned tagf = (unsigned)((TT + 1) & 15);
    if (tid < 375) {
      const unsigned* ap = myrep + (tid << 2);   // slot 0 of own replica
      uv4 v;
      for (;;) {
        asm volatile("global_load_dwordx4 %0, %1, off sc0 sc1\n\t"
                     "s_waitcnt vmcnt(0)"
                     : "=&v"(v) : "v"(ap) : "memory");
        const unsigned miss = ((v.x & 15u) ^ tagf) | ((v.y & 15u) ^ tagf)
                            | ((v.z & 15u) ^ tagf) | ((v.w & 15u) ^ tagf);
        if (!miss) break;
        __builtin_amdgcn_s_sleep(1);
      }
      float4 f = {__uint_as_float(v.x), __uint_as_float(v.y),
                  __uint_as_float(v.z), __uint_as_float(v.w)};
      *(float4*)(lds_hf + (tid << 2)) = f;
    } else if (tid < 384) {
      float4 z4 = {0.f, 0.f, 0.f, 0.f};
      *(float4*)(lds_hf + (tid << 2)) = z4;
    }
  }
  __syncthreads();

  // ---- MLP layer 1: 15 rows/block, r = bid + 125*k, k = wv, wv+8 ----
  {
    const float4* h4 = (const float4*)lds_hf;
    for (int k = wv; k < 15; k += 8) {
      const int r = bid + NB * k;
      const float4* wrow = (const float4*)(W1 + (size_t)r * HH);
      float ss = 0.f;
      #pragma unroll
      for (int m = 0; m < 6; ++m) {
        const int idx = ln + 64 * m;
        if (idx < 375) {
          const float4 a = wrow[idx], hv = h4[idx];
          ss += a.x*hv.x + a.y*hv.y + a.z*hv.z + a.w*hv.w;
        }
      }
      #pragma unroll
      for (int off = 32; off > 0; off >>= 1) ss += __shfl_xor(ss, off, 64);
      if (ln == 0) {
        const float vv = ss + b1[r];
        AST4(hidp + r, (__float_as_uint(vv) & ~15u) | 5u);  // tag 5 != poison 10
      }
    }
  }
  if (bid != 0) return;

  // ---- block 0: gather hid (into lds_wh alias), MLP layer 2, write out ----
  __syncthreads();
  for (int j = tid; j < 1875; j += NT) {
    unsigned bts;
    for (;;) {
      bts = ALD4(hidp + j);
      if ((bts & 15u) == 5u) break;
      __builtin_amdgcn_s_sleep(1);
    }
    lds_hd[j] = __uint_as_float(bts);
  }
  __syncthreads();

  for (int r = wv; r < 20; r += 8) {
    float ss = 0.f;
    for (int k = ln; k < 1875; k += 64)
      ss = fmaf(W2[(size_t)r * 1875 + k], lds_hd[k], ss);
    #pragma unroll
    for (int off = 32; off > 0; off >>= 1) ss += __shfl_xor(ss, off, 64);
    if (ln == 0) out[r] = ss + b2[r];
  }
}

extern "C" void kernel_launch(void* const* d_in, const int* in_sizes, int n_in,
                              void* d_out, int out_size, void* d_ws, size_t ws_size,
                              hipStream_t stream) {
  const float* x   = (const float*)d_in[0];
  const float* Wih = (const float*)d_in[1];
  const float* Whh = (const float*)d_in[2];
  const float* bih = (const float*)d_in[3];
  const float* bhh = (const float*)d_in[4];
  const float* W1  = (const float*)d_in[5];
  const float* b1  = (const float*)d_in[6];
  const float* W2  = (const float*)d_in[7];
  const float* b2  = (const float*)d_in[8];
  float* out   = (float*)d_out;
  unsigned* ws = (unsigned*)d_ws;   // uses ~106 KB (8 pub replicas + hidp)

  // 125 blocks x 512 threads, ~159 KB LDS (1 block/CU), 125 <= 256 CUs:
  // all blocks co-resident -> the tagged exchange cannot deadlock.
  hipLaunchKernelGGL(lstm_fused, dim3(NB), dim3(NT), 0, stream,
                     x, Wih, Whh, bih, bhh, W1, b1, W2, b2, out, ws);
}

// Round 9
// 10267.653 us; speedup vs baseline: 1.0708x; 1.0199x over previous
//
#include <hip/hip_runtime.h>
#include <math.h>

#define TT 4096
#define HH 1500
#define NB 125     // blocks; each owns 12 hidden units (R17: halved population)
#define NT 512     // 8 waves: 0..5 matvec (wave = 2 units, 8 gate rows),
                   //          6 = x-proj + poll, 7 = poll + gates + publish
#define NREP 8     // pub replicas (reader sharding; bid&7 ~ XCD id)

typedef unsigned uv4 __attribute__((ext_vector_type(4)));
typedef _Float16 h2f __attribute__((ext_vector_type(2)));
typedef _Float16 h4f __attribute__((ext_vector_type(4)));

#define ALD4(p)   __hip_atomic_load((p), __ATOMIC_RELAXED, __HIP_MEMORY_SCOPE_AGENT)
#define AST4(p,v) __hip_atomic_store((p), (v), __ATOMIC_RELAXED, __HIP_MEMORY_SCOPE_AGENT)
#define AST8(p,v) __hip_atomic_store((p), (v), __ATOMIC_RELAXED, __HIP_MEMORY_SCOPE_AGENT)

__device__ __forceinline__ float fast_sigmoid(float z) {
  return 1.0f / (1.0f + __expf(-z));
}
__device__ __forceinline__ float fast_tanh(float z) {
  float az = fabsf(z);
  float e  = __expf(-2.0f * az);
  float r  = (1.0f - e) / (1.0f + e);
  return copysignf(r, z);
}
// fp16 pair dot with fp32 accumulate (v_dot2_f32_f16)
__device__ __forceinline__ float dot2(unsigned wb, unsigned hb, float acc) {
#if __has_builtin(__builtin_amdgcn_fdot2)
  return __builtin_amdgcn_fdot2(__builtin_bit_cast(h2f, wb),
                                __builtin_bit_cast(h2f, hb), acc, false);
#else
  h2f w = __builtin_bit_cast(h2f, wb), h = __builtin_bit_cast(h2f, hb);
  acc = fmaf((float)w.x, (float)h.x, acc);
  return fmaf((float)w.y, (float)h.y, acc);
#endif
}

// R20: TERMINAL REVERT to R17 (best harness-verified: 10242us, Round 6).
// Nine-lever ledger (R11-R19): replicas -12%, req width -7%, coupling 0,
// line-exclusive -10%R, 1-barrier schedule -45%R, sampling x3 -20%R,
// population /2 -4% WIN, sampling x2 -9%R, k-sliced arrival -3%R.
// Counters throughout: HBM <=1.2%, VALU 9-17%, Mfma 0, conflicts 0 ->
// never memory/compute-bound. The op is a strictly sequential chain of
// 4096 device-wide all-to-all exchanges; per-step ~5900cy = agent-scope
// store -> IC visibility -> detect round-trip (~2x fabric latency) + max-
// over-125 straggler tail + ~1000cy local work. Compute/step ~300cy (3
// orders under the vector roofline). Binding resource: fabric latency.
// Structure: 125 blocks x 12 units; 48 W_hh rows in LDS (147KB, 1 blk/CU);
// waves 0..5 = 2 units each (24 b128 prefetch overlapping the poll, dual
// accumulators); waves 6..7 poll 12 dwords/lane (3x dwordx4, tag-per-dword,
// sleep(1)); wave 6 x-proj from registers; wave 7 gates + coalesced
// 48-lane dwordx2 publish to 8 replicas.
__device__ __forceinline__ void poll3(const unsigned* a0, const unsigned* a1,
                                      const unsigned* a2,
                                      uv4& v0, uv4& v1, uv4& v2) {
  asm volatile(
      "global_load_dwordx4 %0, %3, off sc0 sc1\n\t"
      "global_load_dwordx4 %1, %4, off sc0 sc1\n\t"
      "global_load_dwordx4 %2, %5, off sc0 sc1\n\t"
      "s_waitcnt vmcnt(0)"
      : "=&v"(v0), "=&v"(v1), "=&v"(v2)
      : "v"(a0), "v"(a1), "v"(a2)
      : "memory");
}
__device__ __forceinline__ h4f cvt4h(uv4 v) {
  h4f r;
  r.x = (_Float16)__uint_as_float(v.x);
  r.y = (_Float16)__uint_as_float(v.y);
  r.z = (_Float16)__uint_as_float(v.z);
  r.w = (_Float16)__uint_as_float(v.w);
  return r;
}

__global__
__attribute__((amdgpu_flat_work_group_size(NT, NT), amdgpu_waves_per_eu(2, 2)))
void lstm_fused(
    const float* __restrict__ x,    // (4096, 20)
    const float* __restrict__ Wih,  // (6000, 20)
    const float* __restrict__ Whh,  // (6000, 1500)
    const float* __restrict__ bih,  // (6000,)
    const float* __restrict__ bhh,  // (6000,)
    const float* __restrict__ W1,   // (1875, 1500)
    const float* __restrict__ b1,   // (1875,)
    const float* __restrict__ W2,   // (20, 1875)
    const float* __restrict__ b2,   // (20,)
    float* __restrict__ out,        // (20,)
    unsigned* __restrict__ ws)
{
  const int tid = threadIdx.x;
  const int bid = blockIdx.x;
  const int wv  = tid >> 6;   // wave 0..7
  const int ln  = tid & 63;

  // pub: [NREP][2][1536] tagged dwords; block b owns dwords 12b..12b+11 of
  // each replica/slot. hidp after.
  unsigned* pub  = ws;
  unsigned* hidp = ws + NREP * 2 * 1536;   // [1875] tagged hid values

  // weights: 48 rows (r=u*4+g) x 1536 halves (1500 + zero pad) = 147,456 B
  __shared__ __align__(16) _Float16 lds_wh[48 * 1536];
  __shared__ __align__(16) _Float16 lds_hh[1536];  // h(t) as fp16
  __shared__ __align__(16) float    lds_hf[1536];  // h(TT) fp32 for MLP
  __shared__ float lds_xp[2][48];                  // x-proj dbuf: [par][g*12+u]
  __shared__ float lds_gs[4][12];                  // gate sums: [g][u]
  float* lds_hd = (float*)lds_wh;                  // alias (block 0, post-loop)
  // total ~157.2 KB < 160 KiB -> exactly 1 block/CU (lockstep chain intact)

  // ---- stage W_hh slice into LDS, converting fp32 -> fp16 ----
  for (int hi = tid; hi < 48 * 1536; hi += NT) {
    const int r = hi / 1536, k = hi - r * 1536;
    const int u = r >> 2, g = r & 3;
    const size_t grow = (size_t)(g * HH + bid * 12 + u) * HH;
    const float v = (k < HH) ? Whh[grow + k] : 0.f;
    lds_wh[hi] = (_Float16)v;
  }

  // matvec bases (waves 0..5): wave wv owns units 2wv, 2wv+1; 192 b128/row
  const int uu = (wv < 6) ? wv : 0;
  const uv4* wpA = ((const uv4*)lds_wh) + (size_t)(2 * uu) * 4 * 192;
  const uv4* wpB = wpA + 4 * 192;
  const uv4* hp = (const uv4*)lds_hh;

  // ---- wave 6 lanes 0..47: persistent Wih row (g=ln/12, u=ln%12) + x(0) ----
  float4 wx0, wx1, wx2, wx3, wx4;
  float4 xr0, xr1, xr2, xr3, xr4;
  float bias = 0.f;
  if (wv == 6 && ln < 48) {
    const int g = ln / 12, u = ln - g * 12;
    const int row = g * HH + bid * 12 + u;
    const float4* sp = (const float4*)(Wih + row * 20);
    wx0 = sp[0]; wx1 = sp[1]; wx2 = sp[2]; wx3 = sp[3]; wx4 = sp[4];
    bias = bih[row] + bhh[row];
    const float4* xx = (const float4*)x;
    xr0 = xx[0]; xr1 = xx[1]; xr2 = xx[2]; xr3 = xx[3]; xr4 = xx[4];
  }

  float c = 0.f;  // cell state: wave 7 lanes 0..11 (unit = ln)

  // init publish: h(0)=0 with tag 1 into ALL replicas, slot 0
  if (tid < 12 * NREP)
    AST4(pub + (tid / 12) * 3072 + 12 * bid + (tid % 12), 1u);

  __syncthreads();   // weights staged

  // this block's poll replica
  unsigned* myrep = pub + (bid & (NREP - 1)) * 3072;

  for (int t = 0; t < TT; ++t) {
    const int s = t & 1;
    const unsigned tag = (unsigned)((t + 1) & 15);

    // ================= P phase (pre-A) =================
    uv4 pw[24];
    if (wv < 6) {
      // prefetch ALL 24 weight b128 (96 VGPRs) — overlaps the poll below
      #pragma unroll
      for (int g = 0; g < 4; ++g) {
        #pragma unroll
        for (int m = 0; m < 3; ++m) {
          pw[g * 3 + m]      = wpA[g * 192 + ln + 64 * m];
          pw[12 + g * 3 + m] = wpB[g * 192 + ln + 64 * m];
        }
      }
    } else {
      if (wv == 6 && ln < 48) {
        // x-projection for step t (from registers, h-independent)
        float sx = bias;
        sx += wx0.x*xr0.x + wx0.y*xr0.y + wx0.z*xr0.z + wx0.w*xr0.w;
        sx += wx1.x*xr1.x + wx1.y*xr1.y + wx1.z*xr1.z + wx1.w*xr1.w;
        sx += wx2.x*xr2.x + wx2.y*xr2.y + wx2.z*xr2.z + wx2.w*xr2.w;
        sx += wx3.x*xr3.x + wx3.y*xr3.y + wx3.z*xr3.z + wx3.w*xr3.w;
        sx += wx4.x*xr4.x + wx4.y*xr4.y + wx4.z*xr4.z + wx4.w*xr4.w;
        lds_xp[s][ln] = sx;
      }
      // ---- coalesced tagged poll of replica bid&7 (R12 structure) ----
      const int p4 = (tid - 384) << 2;        // 0,4,...,508
      unsigned* base = myrep + s * 1536;
      uv4 v0, v1, v2;
      for (;;) {
        poll3(base + p4, base + p4 + 512, base + p4 + 1024, v0, v1, v2);
        unsigned miss = ((v0.x & 15u) ^ tag) | ((v0.y & 15u) ^ tag)
                      | ((v0.z & 15u) ^ tag) | ((v0.w & 15u) ^ tag)
                      | ((v1.x & 15u) ^ tag) | ((v1.y & 15u) ^ tag)
                      | ((v1.z & 15u) ^ tag) | ((v1.w & 15u) ^ tag);
        if (p4 + 1024 < HH)   // chunk-uniform: 1500 = 4*375
          miss |= ((v2.x & 15u) ^ tag) | ((v2.y & 15u) ^ tag)
                | ((v2.z & 15u) ^ tag) | ((v2.w & 15u) ^ tag);
        if (!__any(miss != 0u)) break;
        __builtin_amdgcn_s_sleep(1);
      }
      *(h4f*)(lds_hh + p4)       = cvt4h(v0);
      *(h4f*)(lds_hh + p4 + 512) = cvt4h(v1);
      h4f z = {(_Float16)0.f, (_Float16)0.f, (_Float16)0.f, (_Float16)0.f};
      *(h4f*)(lds_hh + p4 + 1024) = (p4 + 1024 < HH) ? cvt4h(v2) : z;
    }
    __syncthreads();   // ---- A: h(t) fp16, xp(t) staged ----

    // ================= M phase =================
    if (wv < 6) {
      uv4 hv[3];
      #pragma unroll
      for (int m = 0; m < 3; ++m) hv[m] = hp[ln + 64 * m];
      float a0[4] = {0.f, 0.f, 0.f, 0.f};
      float a1[4] = {0.f, 0.f, 0.f, 0.f};
      #pragma unroll
      for (int g = 0; g < 4; ++g) {
        #pragma unroll
        for (int m = 0; m < 3; ++m) {
          const uv4 h = hv[m];
          const uv4 qa = pw[g * 3 + m];
          a0[g] = dot2(qa.x, h.x, a0[g]);
          a0[g] = dot2(qa.y, h.y, a0[g]);
          a0[g] = dot2(qa.z, h.z, a0[g]);
          a0[g] = dot2(qa.w, h.w, a0[g]);
          const uv4 qb = pw[12 + g * 3 + m];
          a1[g] = dot2(qb.x, h.x, a1[g]);
          a1[g] = dot2(qb.y, h.y, a1[g]);
          a1[g] = dot2(qb.z, h.z, a1[g]);
          a1[g] = dot2(qb.w, h.w, a1[g]);
        }
      }
      // fold-select reduce (x2 units)
      #pragma unroll
      for (int g = 0; g < 4; ++g) {
        a0[g] += __shfl_xor(a0[g], 16, 64);
        a0[g] += __shfl_xor(a0[g], 32, 64);
        a1[g] += __shfl_xor(a1[g], 16, 64);
        a1[g] += __shfl_xor(a1[g], 32, 64);
      }
      const int q4 = ln >> 4;
      float v0 = (q4 == 0) ? a0[0] : (q4 == 1) ? a0[1] : (q4 == 2) ? a0[2] : a0[3];
      float v1 = (q4 == 0) ? a1[0] : (q4 == 1) ? a1[1] : (q4 == 2) ? a1[2] : a1[3];
      #pragma unroll
      for (int off = 1; off <= 8; off <<= 1) {
        v0 += __shfl_xor(v0, off, 64);
        v1 += __shfl_xor(v1, off, 64);
      }
      if ((ln & 15) == 0) {
        lds_gs[q4][2 * wv]     = v0;
        lds_gs[q4][2 * wv + 1] = v1;
      }
    } else if (wv == 6 && ln < 48 && (t + 1) < TT) {
      // prefetch x(t+1) while waves 0-5 compute
      const float4* xx = (const float4*)(x + 20 * (t + 1));
      xr0 = xx[0]; xr1 = xx[1]; xr2 = xx[2]; xr3 = xx[3]; xr4 = xx[4];
    }
    __syncthreads();   // ---- B: gate sums ready ----

    // ================= G phase: wave 7 only =================
    if (wv == 7) {
      unsigned bits = 0u;
      if (ln < 12) {
        const int u = ln;
        const float zi = lds_gs[0][u] + lds_xp[s][0 + u];
        const float zf = lds_gs[1][u] + lds_xp[s][12 + u];
        const float zg = lds_gs[2][u] + lds_xp[s][24 + u];
        const float zo = lds_gs[3][u] + lds_xp[s][36 + u];
        const float ig = fast_sigmoid(zi);
        const float fg = fast_sigmoid(zf);
        const float gg = fast_tanh(zg);
        const float og = fast_sigmoid(zo);
        c = fg * c + ig * gg;
        const float hn = og * fast_tanh(c);
        bits = (__float_as_uint(hn) & ~15u) | (unsigned)((t + 2) & 15);
      }
      // publish 12 tagged dwords x 8 replicas: lanes 0..47, dwordx2 each
      const int m6 = ln % 6;
      const unsigned d0 = (unsigned)__shfl((int)bits, 2 * m6, 64);
      const unsigned d1 = (unsigned)__shfl((int)bits, 2 * m6 + 1, 64);
      if (ln < 48) {
        const int rep = ln / 6;
        const unsigned long long dd =
            (unsigned long long)d0 | ((unsigned long long)d1 << 32);
        AST8((unsigned long long*)(pub + rep * 3072 + ((t + 1) & 1) * 1536 +
                                   12 * bid + 2 * m6), dd);
      }
    }
  }

  // ---- final gather h(TT) fp32 into lds_hf (slot 0, tag 1) ----
  {
    const unsigned tagf = (unsigned)((TT + 1) & 15);
    if (tid < 375) {
      const unsigned* ap = myrep + (tid << 2);   // slot 0 of own replica
      uv4 v;
      for (;;) {
        asm volatile("global_load_dwordx4 %0, %1, off sc0 sc1\n\t"
                     "s_waitcnt vmcnt(0)"
                     : "=&v"(v) : "v"(ap) : "memory");
        const unsigned miss = ((v.x & 15u) ^ tagf) | ((v.y & 15u) ^ tagf)
                            | ((v.z & 15u) ^ tagf) | ((v.w & 15u) ^ tagf);
        if (!miss) break;
        __builtin_amdgcn_s_sleep(1);
      }
      float4 f = {__uint_as_float(v.x), __uint_as_float(v.y),
                  __uint_as_float(v.z), __uint_as_float(v.w)};
      *(float4*)(lds_hf + (tid << 2)) = f;
    } else if (tid < 384) {
      float4 z4 = {0.f, 0.f, 0.f, 0.f};
      *(float4*)(lds_hf + (tid << 2)) = z4;
    }
  }
  __syncthreads();

  // ---- MLP layer 1: 15 rows/block, r = bid + 125*k, k = wv, wv+8 ----
  {
    const float4* h4 = (const float4*)lds_hf;
    for (int k = wv; k < 15; k += 8) {
      const int r = bid + NB * k;
      const float4* wrow = (const float4*)(W1 + (size_t)r * HH);
      float ss = 0.f;
      #pragma unroll
      for (int m = 0; m < 6; ++m) {
        const int idx = ln + 64 * m;
        if (idx < 375) {
          const float4 a = wrow[idx], hv = h4[idx];
          ss += a.x*hv.x + a.y*hv.y + a.z*hv.z + a.w*hv.w;
        }
      }
      #pragma unroll
      for (int off = 32; off > 0; off >>= 1) ss += __shfl_xor(ss, off, 64);
      if (ln == 0) {
        const float vv = ss + b1[r];
        AST4(hidp + r, (__float_as_uint(vv) & ~15u) | 5u);  // tag 5 != poison 10
      }
    }
  }
  if (bid != 0) return;

  // ---- block 0: gather hid (into lds_wh alias), MLP layer 2, write out ----
  __syncthreads();
  for (int j = tid; j < 1875; j += NT) {
    unsigned bts;
    for (;;) {
      bts = ALD4(hidp + j);
      if ((bts & 15u) == 5u) break;
      __builtin_amdgcn_s_sleep(1);
    }
    lds_hd[j] = __uint_as_float(bts);
  }
  __syncthreads();

  for (int r = wv; r < 20; r += 8) {
    float ss = 0.f;
    for (int k = ln; k < 1875; k += 64)
      ss = fmaf(W2[(size_t)r * 1875 + k], lds_hd[k], ss);
    #pragma unroll
    for (int off = 32; off > 0; off >>= 1) ss += __shfl_xor(ss, off, 64);
    if (ln == 0) out[r] = ss + b2[r];
  }
}

extern "C" void kernel_launch(void* const* d_in, const int* in_sizes, int n_in,
                              void* d_out, int out_size, void* d_ws, size_t ws_size,
                              hipStream_t stream) {
  const float* x   = (const float*)d_in[0];
  const float* Wih = (const float*)d_in[1];
  const float* Whh = (const float*)d_in[2];
  const float* bih = (const float*)d_in[3];
  const float* bhh = (const float*)d_in[4];
  const float* W1  = (const float*)d_in[5];
  const float* b1  = (const float*)d_in[6];
  const float* W2  = (const float*)d_in[7];
  const float* b2  = (const float*)d_in[8];
  float* out   = (float*)d_out;
  unsigned* ws = (unsigned*)d_ws;   // uses ~106 KB (8 pub replicas + hidp)

  // 125 blocks x 512 threads, ~157 KB LDS (1 block/CU), 125 <= 256 CUs:
  // all blocks co-resident -> the tagged exchange cannot deadlock.
  hipLaunchKernelGGL(lstm_fused, dim3(NB), dim3(NT), 0, stream,
                     x, Wih, Whh, bih, bhh, W1, b1, W2, b2, out, ws);
}